// Round 7
// baseline (91.343 us; speedup 1.0000x reference)
//
#include <hip/hip_runtime.h>

#define Nn 256
#define Cc 128
#define Pp 275
#define Dd 128

typedef unsigned int u32;
typedef unsigned short u16;
typedef float f32x4 __attribute__((ext_vector_type(4)));
typedef short bf16x8 __attribute__((ext_vector_type(8)));

__device__ __forceinline__ float bf2f(u16 h) {
    return __uint_as_float(((u32)h) << 16);
}
__device__ __forceinline__ u16 f2bf(float f) {
    u32 u = __float_as_uint(f);
    return (u16)((u + 0x7fffu + ((u >> 16) & 1u)) >> 16);
}

// ---------------- K1: bias_t / bias_p (N x D) + f->bf16 + Wl^T bf16 ----------------
__global__ __launch_bounds__(256) void bias_kernel(
    const float* __restrict__ m_t, const float* __restrict__ m_p,
    const float* __restrict__ c_t, const float* __restrict__ c_p,
    const float* __restrict__ W, const float* __restrict__ b,
    const float* __restrict__ f,
    float* __restrict__ bias_t, float* __restrict__ bias_p,
    u16* __restrict__ f_bf, u16* __restrict__ WlT)
{
    int idx = blockIdx.x * 256 + threadIdx.x;   // N*D = 32768
    int n = idx >> 7, d = idx & 127;
    float at = 0.f, ap = 0.f;
#pragma unroll 8
    for (int k = 0; k < 64; ++k) {
        float wm = W[(128 + k) * 128 + d];
        float wc = W[(192 + k) * 128 + d];
        at = fmaf(m_t[n * 64 + k], wm, at);
        at = fmaf(c_t[n * 64 + k], wc, at);
        ap = fmaf(m_p[n * 64 + k], wm, ap);
        ap = fmaf(c_p[n * 64 + k], wc, ap);
    }
    float bb = b[d];
    bias_t[idx] = at + bb;
    bias_p[idx] = ap + bb;
    f_bf[idx] = f2bf(f[idx]);
    if (idx < 16384) {                 // WlT[d][c] = Wl[c][d]
        int dd = idx >> 7, cc = idx & 127;
        WlT[idx] = f2bf(W[cc * 128 + dd]);
    }
}

// ---------------- K2: join, no LDS — B-frags straight from L1-resident WlT ----------
// grid (5, 256, 2): z = pass (0: x_t->pred, 1: x_p->pos); 4 waves/block,
// wave owns p-tile t = blockIdx.x*4 + wave (t<18). No barriers, no LDS.
__global__ __launch_bounds__(256) void join_nolds_kernel(
    const float* __restrict__ x_t, const float* __restrict__ x_p,
    const u16* __restrict__ WlT,
    const float* __restrict__ bias_t, const float* __restrict__ bias_p,
    u16* __restrict__ pred, u16* __restrict__ pos)
{
    const int tid = threadIdx.x;
    const int n = blockIdx.y;
    const int pass = blockIdx.z;
    const int w = tid >> 6;
    const int l = tid & 63;
    const int t = blockIdx.x * 4 + w;          // 0..19, 18 used
    if (t >= 18) return;

    const float* xg  = pass ? x_p : x_t;
    const float* bias = pass ? bias_p : bias_t;
    u16* outp = pass ? pos : pred;

    const int p0 = t * 16;
    int prow = p0 + (l & 15);
    if (prow > Pp - 1) prow = Pp - 1;          // clamp tail reads (stores masked)

    const float* xs = xg + (size_t)n * (Cc * Pp) + prow;
    const int cg = (l >> 4) << 3;

    // issue all 32 x loads, then fence so the compiler can't sink them
    float v[32];
#pragma unroll
    for (int kk = 0; kk < 4; ++kk) {
        const size_t cb = (size_t)(kk * 32 + cg) * Pp;
#pragma unroll
        for (int e = 0; e < 8; ++e) v[kk * 8 + e] = xs[cb + (size_t)e * Pp];
    }
    asm volatile("" ::: "memory");

    bf16x8 A[4];
#pragma unroll
    for (int kk = 0; kk < 4; ++kk) {
        bf16x8 a;
#pragma unroll
        for (int e = 0; e < 8; ++e) a[e] = (short)f2bf(v[kk * 8 + e]);
        A[kk] = a;
    }

    float bv[8];
#pragma unroll
    for (int dt = 0; dt < 8; ++dt) bv[dt] = bias[n * 128 + dt * 16 + (l & 15)];

    const char* Bbase = (const char*)WlT + ((l & 15) << 8) + ((l >> 4) << 4);

#pragma unroll
    for (int dt = 0; dt < 8; ++dt) {
        bf16x8 B[4];
#pragma unroll
        for (int kk = 0; kk < 4; ++kk)
            B[kk] = *reinterpret_cast<const bf16x8*>(Bbase + dt * 4096 + kk * 64);
        f32x4 acc = {0.f, 0.f, 0.f, 0.f};
#pragma unroll
        for (int kk = 0; kk < 4; ++kk)
            acc = __builtin_amdgcn_mfma_f32_16x16x32_bf16(A[kk], B[kk], acc, 0, 0, 0);
        const int d = dt * 16 + (l & 15);
#pragma unroll
        for (int r = 0; r < 4; ++r) {
            int p = p0 + ((l >> 4) << 2) + r;
            if (p < Pp) outp[((size_t)p * Nn + n) * Dd + d] = f2bf(acc[r] + bv[dt]);
        }
    }
}

// ---------------- K3: MFMA logits + fixed-shift LSE - diag (R5 structure) ----------
// grid (Pp, 2): sel = blockIdx.y (0: S1=f.pos^T, 1: S2=pred.pos^T).
// 512 threads = 8 waves; wave w owns rows w*32..w*32+31 (2 row-tiles of 16).
__global__ __launch_bounds__(512) void logits_mfma_kernel(
    const u16* __restrict__ f_bf,
    const u16* __restrict__ pred, const u16* __restrict__ pos,
    float* __restrict__ partial)
{
    __shared__ u16 lds[Nn * Dd];   // 64 KB swizzled pos[p] tile
    const int tid = threadIdx.x;
    const int p = blockIdx.x;
    const int sel = blockIdx.y;
    const int w = tid >> 6;
    const int l = tid & 63;
    const int r0 = w * 32;

    {
        const uint4* src = reinterpret_cast<const uint4*>(pos + (size_t)p * (Nn * Dd));
#pragma unroll
        for (int it = 0; it < 8; ++it) {
            int j = tid + 512 * it;
            int row = j >> 4;
            int colb = (j & 15) << 4;
            uint4 v = src[j];
            *reinterpret_cast<uint4*>((char*)lds + row * 256 + (colb ^ ((row & 7) << 4))) = v;
        }
    }

    const u16* Abase = sel ? (pred + (size_t)p * (Nn * Dd)) : f_bf;
    bf16x8 A[2][4];
    {
        const int arow = l & 15;
        const int acol = (l >> 4) << 4;
#pragma unroll
        for (int rt = 0; rt < 2; ++rt)
#pragma unroll
            for (int kk = 0; kk < 4; ++kk) {
                const char* ap = (const char*)Abase
                               + (size_t)(r0 + rt * 16 + arow) * 256 + kk * 64 + acol;
                A[rt][kk] = *reinterpret_cast<const bf16x8*>(ap);
            }
    }

    __syncthreads();

    const float L2E = 1.4426950408889634f;
    float s_[2][4];
    float dg[2][4];
#pragma unroll
    for (int rt = 0; rt < 2; ++rt)
#pragma unroll
        for (int r = 0; r < 4; ++r) { s_[rt][r] = 0.f; dg[rt][r] = 0.f; }

    const int mcol = l & 15;
    const int bcol = (l >> 4) << 4;

    for (int ct = 0; ct < 16; ++ct) {
        bf16x8 B[4];
        const int mrow = ct * 16 + mcol;
#pragma unroll
        for (int kk = 0; kk < 4; ++kk) {
            int cb = kk * 64 + bcol;
            B[kk] = *reinterpret_cast<const bf16x8*>(
                (const char*)lds + mrow * 256 + (cb ^ ((mrow & 7) << 4)));
        }
#pragma unroll
        for (int rt = 0; rt < 2; ++rt) {
            f32x4 acc = {0.f, 0.f, 0.f, 0.f};
#pragma unroll
            for (int kk = 0; kk < 4; ++kk)
                acc = __builtin_amdgcn_mfma_f32_16x16x32_bf16(A[rt][kk], B[kk], acc, 0, 0, 0);
            const bool isdg_ct = (ct == ((r0 >> 4) + rt));
#pragma unroll
            for (int r = 0; r < 4; ++r) {
                float v = acc[r];
                s_[rt][r] += __builtin_amdgcn_exp2f(fmaf(v, L2E, -64.f));
                if (isdg_ct && ((l & 15) == (((l >> 4) << 2) + r))) dg[rt][r] = v;
            }
        }
    }

    float local = 0.f;
#pragma unroll
    for (int rt = 0; rt < 2; ++rt)
#pragma unroll
        for (int r = 0; r < 4; ++r) {
            float s = s_[rt][r];
            s += __shfl_xor(s, 1);
            s += __shfl_xor(s, 2);
            s += __shfl_xor(s, 4);
            s += __shfl_xor(s, 8);
            if ((l & 15) == (((l >> 4) << 2) + r))
                local += 0.6931471805599453f * (64.f + __log2f(s)) - dg[rt][r];
        }

    __syncthreads();
    float* red = reinterpret_cast<float*>(lds);
    red[tid] = local;
    __syncthreads();
    for (int k = 256; k > 0; k >>= 1) {
        if (tid < k) red[tid] += red[tid + k];
        __syncthreads();
    }
    if (tid == 0) partial[p * 2 + sel] = red[0];
}

// ---------------- K4: deterministic final reduce ----------------
__global__ __launch_bounds__(256) void reduce_kernel(
    const float* __restrict__ partial, float* __restrict__ out)
{
    __shared__ float red[256];
    float s = 0.f;
    for (int i = threadIdx.x; i < 2 * Pp; i += 256) s += partial[i];
    red[threadIdx.x] = s;
    __syncthreads();
    for (int k = 128; k > 0; k >>= 1) {
        if (threadIdx.x < k) red[threadIdx.x] += red[threadIdx.x + k];
        __syncthreads();
    }
    if (threadIdx.x == 0) out[0] = red[0] * (1.0f / (Pp * (float)Nn));
}

extern "C" void kernel_launch(void* const* d_in, const int* in_sizes, int n_in,
                              void* d_out, int out_size, void* d_ws, size_t ws_size,
                              hipStream_t stream)
{
    const float* f   = (const float*)d_in[0];
    const float* x_t = (const float*)d_in[1];
    const float* x_p = (const float*)d_in[2];
    const float* m_t = (const float*)d_in[3];
    const float* m_p = (const float*)d_in[4];
    const float* c_t = (const float*)d_in[5];
    const float* c_p = (const float*)d_in[6];
    const float* W   = (const float*)d_in[7];
    const float* b   = (const float*)d_in[8];

    char* ws = (char*)d_ws;
    const size_t SLAB = (size_t)Pp * Nn * Dd;     // 9,011,200 elems

    float* bias_t = (float*)ws;                          // 131072 B
    float* bias_p = bias_t + Nn * Dd;                    // 131072 B
    u16* f_bf = (u16*)(ws + 262144);                     // 65536 B
    u16* WlT  = f_bf + Nn * Dd;                          // 32768 B
    u16* pred = (u16*)(ws + 360448);
    u16* pos  = pred + SLAB;
    float* partial = (float*)(pos + SLAB);

    bias_kernel<<<dim3(Nn * Dd / 256), 256, 0, stream>>>(m_t, m_p, c_t, c_p, W, b, f,
                                                         bias_t, bias_p, f_bf, WlT);
    join_nolds_kernel<<<dim3(5, Nn, 2), 256, 0, stream>>>(x_t, x_p, WlT, bias_t, bias_p,
                                                          pred, pos);
    logits_mfma_kernel<<<dim3(Pp, 2), 512, 0, stream>>>(f_bf, pred, pos, partial);
    reduce_kernel<<<1, 256, 0, stream>>>(partial, (float*)d_out);
}

// Round 8
// 68.574 us; speedup vs baseline: 1.3320x; 1.3320x over previous
//
#include <hip/hip_runtime.h>

#define Nn 256
#define Cc 128
#define Pp 275
#define Dd 128

typedef unsigned int u32;
typedef unsigned short u16;
typedef float f32x4 __attribute__((ext_vector_type(4)));
typedef short bf16x8 __attribute__((ext_vector_type(8)));

__device__ __forceinline__ float bf2f(u16 h) {
    return __uint_as_float(((u32)h) << 16);
}
__device__ __forceinline__ u16 f2bf(float f) {
    u32 u = __float_as_uint(f);
    return (u16)((u + 0x7fffu + ((u >> 16) & 1u)) >> 16);
}

// ---------------- K1: bias_t / bias_p (N x D) + f->bf16 + Wl^T bf16 ----------------
__global__ __launch_bounds__(256) void bias_kernel(
    const float* __restrict__ m_t, const float* __restrict__ m_p,
    const float* __restrict__ c_t, const float* __restrict__ c_p,
    const float* __restrict__ W, const float* __restrict__ b,
    const float* __restrict__ f,
    float* __restrict__ bias_t, float* __restrict__ bias_p,
    u16* __restrict__ f_bf, u16* __restrict__ WlT)
{
    int idx = blockIdx.x * 256 + threadIdx.x;   // N*D = 32768
    int n = idx >> 7, d = idx & 127;
    float at = 0.f, ap = 0.f;
#pragma unroll 8
    for (int k = 0; k < 64; ++k) {
        float wm = W[(128 + k) * 128 + d];
        float wc = W[(192 + k) * 128 + d];
        at = fmaf(m_t[n * 64 + k], wm, at);
        at = fmaf(c_t[n * 64 + k], wc, at);
        ap = fmaf(m_p[n * 64 + k], wm, ap);
        ap = fmaf(c_p[n * 64 + k], wc, ap);
    }
    float bb = b[d];
    bias_t[idx] = at + bb;
    bias_p[idx] = ap + bb;
    f_bf[idx] = f2bf(f[idx]);
    if (idx < 16384) {                 // WlT[d][c] = Wl[c][d]
        int dd = idx >> 7, cc = idx & 127;
        WlT[idx] = f2bf(W[cc * 128 + dd]);
    }
}

// ---------------- K2: join — 512-thr block per n, 8 waves, WlT in LDS ----------------
// grid 256 (one n per block); wave w handles p-tiles t = w, w+8, w+16 (t<18).
__global__ __launch_bounds__(512) void join_kernel512(
    const float* __restrict__ x_t, const float* __restrict__ x_p,
    const u16* __restrict__ WlT,
    const float* __restrict__ bias_t, const float* __restrict__ bias_p,
    u16* __restrict__ pred, u16* __restrict__ pos)
{
    __shared__ u16 lds[128 * 128];   // 32 KB swizzled WlT
    const int tid = threadIdx.x;
    const int n = blockIdx.x;
    const int w = tid >> 6;
    const int l = tid & 63;

    {   // stage WlT swizzled: 2048 uint4 over 512 threads
        const uint4* src = reinterpret_cast<const uint4*>(WlT);
#pragma unroll
        for (int it = 0; it < 4; ++it) {
            int j = tid + 512 * it;
            int row = j >> 4;
            int colb = (j & 15) << 4;
            uint4 v = src[j];
            *reinterpret_cast<uint4*>((char*)lds + row * 256 + (colb ^ ((row & 7) << 4))) = v;
        }
    }

    float bvT[8], bvP[8];
#pragma unroll
    for (int dt = 0; dt < 8; ++dt) {
        int d = dt * 16 + (l & 15);
        bvT[dt] = bias_t[n * 128 + d];
        bvP[dt] = bias_p[n * 128 + d];
    }

    __syncthreads();

    const float* xbase_t = x_t + (size_t)n * (Cc * Pp);
    const float* xbase_p = x_p + (size_t)n * (Cc * Pp);
    const int cg = (l >> 4) << 3;

    for (int t = w; t < 18; t += 8) {
        const int p0 = t * 16;
        int prow = p0 + (l & 15);
        if (prow > Pp - 1) prow = Pp - 1;      // clamp tail reads (stores masked)
        const float* xs_t = xbase_t + prow;
        const float* xs_p = xbase_p + prow;

        // load + convert A fragments for both passes: lane needs c = kk*32+cg+e
        bf16x8 At[4], Ap[4];
#pragma unroll
        for (int kk = 0; kk < 4; ++kk) {
            const size_t cb = (size_t)(kk * 32 + cg) * Pp;
            float vt[8], vp[8];
#pragma unroll
            for (int e = 0; e < 8; ++e) vt[e] = xs_t[cb + (size_t)e * Pp];
#pragma unroll
            for (int e = 0; e < 8; ++e) vp[e] = xs_p[cb + (size_t)e * Pp];
            bf16x8 a, c;
#pragma unroll
            for (int e = 0; e < 8; ++e) { a[e] = (short)f2bf(vt[e]); c[e] = (short)f2bf(vp[e]); }
            At[kk] = a;
            Ap[kk] = c;
        }

#pragma unroll
        for (int dt = 0; dt < 8; ++dt) {
            bf16x8 B[4];
            const int row = dt * 16 + (l & 15);
#pragma unroll
            for (int kk = 0; kk < 4; ++kk) {
                int cbyte = kk * 64 + ((l >> 4) << 4);
                B[kk] = *reinterpret_cast<const bf16x8*>(
                    (const char*)lds + row * 256 + (cbyte ^ ((row & 7) << 4)));
            }
            f32x4 aT = {0.f, 0.f, 0.f, 0.f}, aP = {0.f, 0.f, 0.f, 0.f};
#pragma unroll
            for (int kk = 0; kk < 4; ++kk) {
                aT = __builtin_amdgcn_mfma_f32_16x16x32_bf16(At[kk], B[kk], aT, 0, 0, 0);
                aP = __builtin_amdgcn_mfma_f32_16x16x32_bf16(Ap[kk], B[kk], aP, 0, 0, 0);
            }
            const int d = dt * 16 + (l & 15);
#pragma unroll
            for (int r = 0; r < 4; ++r) {
                int p = p0 + ((l >> 4) << 2) + r;
                if (p < Pp) {
                    size_t o = ((size_t)p * Nn + n) * Dd + d;
                    pred[o] = f2bf(aT[r] + bvT[dt]);
                    pos[o]  = f2bf(aP[r] + bvP[dt]);
                }
            }
        }
    }
}

// ---------------- K3: MFMA logits + fixed-shift LSE - diag ----------------
// grid (2, Pp): sel = blockIdx.x (adjacent dispatch for L2 reuse of pos[p]).
// 512 threads = 8 waves; wave w owns rows w*32..w*32+31 (2 row-tiles of 16).
__global__ __launch_bounds__(512) void logits_mfma_kernel(
    const u16* __restrict__ f_bf,
    const u16* __restrict__ pred, const u16* __restrict__ pos,
    float* __restrict__ partial)
{
    __shared__ u16 lds[Nn * Dd];   // 64 KB swizzled pos[p] tile
    const int tid = threadIdx.x;
    const int sel = blockIdx.x;
    const int p = blockIdx.y;
    const int w = tid >> 6;
    const int l = tid & 63;
    const int r0 = w * 32;

    {
        const uint4* src = reinterpret_cast<const uint4*>(pos + (size_t)p * (Nn * Dd));
#pragma unroll
        for (int it = 0; it < 8; ++it) {
            int j = tid + 512 * it;
            int row = j >> 4;
            int colb = (j & 15) << 4;
            uint4 v = src[j];
            *reinterpret_cast<uint4*>((char*)lds + row * 256 + (colb ^ ((row & 7) << 4))) = v;
        }
    }

    const u16* Abase = sel ? (pred + (size_t)p * (Nn * Dd)) : f_bf;
    bf16x8 A[2][4];
    {
        const int arow = l & 15;
        const int acol = (l >> 4) << 4;
#pragma unroll
        for (int rt = 0; rt < 2; ++rt)
#pragma unroll
            for (int kk = 0; kk < 4; ++kk) {
                const char* ap = (const char*)Abase
                               + (size_t)(r0 + rt * 16 + arow) * 256 + kk * 64 + acol;
                A[rt][kk] = *reinterpret_cast<const bf16x8*>(ap);
            }
    }

    __syncthreads();

    const float L2E = 1.4426950408889634f;
    float s_[2][4];
    float dg[2][4];
#pragma unroll
    for (int rt = 0; rt < 2; ++rt)
#pragma unroll
        for (int r = 0; r < 4; ++r) { s_[rt][r] = 0.f; dg[rt][r] = 0.f; }

    const int mcol = l & 15;
    const int bcol = (l >> 4) << 4;

    for (int ct = 0; ct < 16; ++ct) {
        bf16x8 B[4];
        const int mrow = ct * 16 + mcol;
#pragma unroll
        for (int kk = 0; kk < 4; ++kk) {
            int cb = kk * 64 + bcol;
            B[kk] = *reinterpret_cast<const bf16x8*>(
                (const char*)lds + mrow * 256 + (cb ^ ((mrow & 7) << 4)));
        }
#pragma unroll
        for (int rt = 0; rt < 2; ++rt) {
            f32x4 acc = {0.f, 0.f, 0.f, 0.f};
#pragma unroll
            for (int kk = 0; kk < 4; ++kk)
                acc = __builtin_amdgcn_mfma_f32_16x16x32_bf16(A[rt][kk], B[kk], acc, 0, 0, 0);
            const bool isdg_ct = (ct == ((r0 >> 4) + rt));
#pragma unroll
            for (int r = 0; r < 4; ++r) {
                float v = acc[r];
                s_[rt][r] += __builtin_amdgcn_exp2f(fmaf(v, L2E, -64.f));
                if (isdg_ct && ((l & 15) == (((l >> 4) << 2) + r))) dg[rt][r] = v;
            }
        }
    }

    float local = 0.f;
#pragma unroll
    for (int rt = 0; rt < 2; ++rt)
#pragma unroll
        for (int r = 0; r < 4; ++r) {
            float s = s_[rt][r];
            s += __shfl_xor(s, 1);
            s += __shfl_xor(s, 2);
            s += __shfl_xor(s, 4);
            s += __shfl_xor(s, 8);
            if ((l & 15) == (((l >> 4) << 2) + r))
                local += 0.6931471805599453f * (64.f + __log2f(s)) - dg[rt][r];
        }

    __syncthreads();
    float* red = reinterpret_cast<float*>(lds);
    red[tid] = local;
    __syncthreads();
    for (int k = 256; k > 0; k >>= 1) {
        if (tid < k) red[tid] += red[tid + k];
        __syncthreads();
    }
    if (tid == 0) partial[p * 2 + sel] = red[0];
}

// ---------------- K4: deterministic final reduce ----------------
__global__ __launch_bounds__(256) void reduce_kernel(
    const float* __restrict__ partial, float* __restrict__ out)
{
    __shared__ float red[256];
    float s = 0.f;
    for (int i = threadIdx.x; i < 2 * Pp; i += 256) s += partial[i];
    red[threadIdx.x] = s;
    __syncthreads();
    for (int k = 128; k > 0; k >>= 1) {
        if (threadIdx.x < k) red[threadIdx.x] += red[threadIdx.x + k];
        __syncthreads();
    }
    if (threadIdx.x == 0) out[0] = red[0] * (1.0f / (Pp * (float)Nn));
}

extern "C" void kernel_launch(void* const* d_in, const int* in_sizes, int n_in,
                              void* d_out, int out_size, void* d_ws, size_t ws_size,
                              hipStream_t stream)
{
    const float* f   = (const float*)d_in[0];
    const float* x_t = (const float*)d_in[1];
    const float* x_p = (const float*)d_in[2];
    const float* m_t = (const float*)d_in[3];
    const float* m_p = (const float*)d_in[4];
    const float* c_t = (const float*)d_in[5];
    const float* c_p = (const float*)d_in[6];
    const float* W   = (const float*)d_in[7];
    const float* b   = (const float*)d_in[8];

    char* ws = (char*)d_ws;
    const size_t SLAB = (size_t)Pp * Nn * Dd;     // 9,011,200 elems

    float* bias_t = (float*)ws;                          // 131072 B
    float* bias_p = bias_t + Nn * Dd;                    // 131072 B
    u16* f_bf = (u16*)(ws + 262144);                     // 65536 B
    u16* WlT  = f_bf + Nn * Dd;                          // 32768 B
    u16* pred = (u16*)(ws + 360448);
    u16* pos  = pred + SLAB;
    float* partial = (float*)(pos + SLAB);

    bias_kernel<<<dim3(Nn * Dd / 256), 256, 0, stream>>>(m_t, m_p, c_t, c_p, W, b, f,
                                                         bias_t, bias_p, f_bf, WlT);
    join_kernel512<<<dim3(Nn), 512, 0, stream>>>(x_t, x_p, WlT, bias_t, bias_p,
                                                 pred, pos);
    logits_mfma_kernel<<<dim3(2, Pp), 512, 0, stream>>>(f_bf, pred, pos, partial);
    reduce_kernel<<<1, 256, 0, stream>>>(partial, (float*)d_out);
}